// Round 2
// baseline (599.476 us; speedup 1.0000x reference)
//
#include <hip/hip_runtime.h>
#include <hip/hip_bf16.h>

// DynamicMaskAttention fused pipeline for MI355X (gfx950).
// B=2, S=2048, HID=1024, H=16, KVH=8, HD=64, KEEP=1024, RATIO=0.7 -> kth=716 (idx 715)

typedef __attribute__((ext_vector_type(8))) short bf16x8;
typedef __attribute__((ext_vector_type(4))) float f32x4;

#define FMIN (-3.4028234663852886e38f)

__device__ __forceinline__ short bf16s(float x) {
  __hip_bfloat16 h = __float2bfloat16(x);
  return __builtin_bit_cast(short, h);
}

__device__ __forceinline__ void gload_lds16(const void* g, void* l) {
  __builtin_amdgcn_global_load_lds(
      (__attribute__((address_space(1))) void*)(void*)(g),
      (__attribute__((address_space(3))) void*)(l), 16, 0, 0);
}

// ---------------- f32 -> bf16 conversion, 4 elems/thread ----------------
__global__ void cvt_kernel(const float* __restrict__ src,
                           __hip_bfloat16* __restrict__ dst, int n4) {
  int i = blockIdx.x * 256 + threadIdx.x;
  if (i >= n4) return;
  float4 v = reinterpret_cast<const float4*>(src)[i];
  ushort4 o;
  o.x = (unsigned short)bf16s(v.x);
  o.y = (unsigned short)bf16s(v.y);
  o.z = (unsigned short)bf16s(v.z);
  o.w = (unsigned short)bf16s(v.w);
  reinterpret_cast<ushort4*>(dst)[i] = o;
}

// ---------------- Wcomb = Wdt @ Wv  (16 x 1024), f32 exact path ----------------
__global__ void wcomb_kernel(const float* __restrict__ Wdt, const float* __restrict__ Wv,
                             float* __restrict__ Wcomb) {
  int t = blockIdx.x * 256 + threadIdx.x;  // 16384 total
  int h = t >> 10, c = t & 1023;
  float acc = 0.f;
  for (int d = 0; d < 512; ++d)
    acc = fmaf(Wdt[h * 512 + d], Wv[d * 1024 + c], acc);
  Wcomb[t] = acc;
}

// ---------------- dyn[b,h,s] = exp(A[h]*softplus(hidden[b,s,:] . Wcomb[h,:])) ----------------
__global__ void dyn_kernel(const float* __restrict__ hidden, const float* __restrict__ Wcomb,
                           const float* __restrict__ A, float* __restrict__ dyn) {
  int t = blockIdx.x * 256 + threadIdx.x;  // 65536 total
  int bs = t >> 4, h = t & 15;
  const float4* hv = reinterpret_cast<const float4*>(hidden + (size_t)bs * 1024);
  const float4* wv = reinterpret_cast<const float4*>(Wcomb + (size_t)h * 1024);
  float acc = 0.f;
#pragma unroll 8
  for (int c = 0; c < 256; ++c) {
    float4 a = hv[c], b = wv[c];
    acc += a.x * b.x + a.y * b.y + a.z * b.z + a.w * b.w;
  }
  float sp = fmaxf(acc, 0.f) + log1pf(expf(-fabsf(acc)));  // jax softplus = logaddexp(x,0)
  float dv = expf(A[h] * sp);
  int b = bs >> 11, s = bs & 2047;
  dyn[(((size_t)(b * 16 + h)) << 11) + s] = dv;
}

// ---------------- per-(b,h): rate = 716th smallest of dyn (bitonic sort in LDS) ----------------
__global__ void rate_kernel(const float* __restrict__ dyn, float* __restrict__ rate) {
  __shared__ float buf[2048];
  int bh = blockIdx.x;
  const float* src = dyn + ((size_t)bh << 11);
  for (int i = threadIdx.x; i < 2048; i += 256) buf[i] = src[i];
  __syncthreads();
  for (int k = 2; k <= 2048; k <<= 1) {
    for (int j = k >> 1; j > 0; j >>= 1) {
      for (int i = threadIdx.x; i < 2048; i += 256) {
        int ixj = i ^ j;
        if (ixj > i) {
          float a = buf[i], b = buf[ixj];
          bool up = ((i & k) == 0);
          if (up ? (a > b) : (a < b)) { buf[i] = b; buf[ixj] = a; }
        }
      }
      __syncthreads();
    }
  }
  if (threadIdx.x == 0) rate[bh] = buf[715];
}

// ---------------- bf16 GEMM C = A @ B^T, 128x128 tile, BK=32, 4 waves ----------------
// MODE 0: QKV projection epilogue (fused RoPE + scatter to per-head bf16 layouts)
// MODE 1: plain f32 output (final Wo projection -> d_out)
template <int MODE>
__global__ __launch_bounds__(256) void gemm_bt(
    const __hip_bfloat16* __restrict__ A, const __hip_bfloat16* __restrict__ Bm,
    float* __restrict__ Cout,
    __hip_bfloat16* __restrict__ Qb, __hip_bfloat16* __restrict__ Kb,
    __hip_bfloat16* __restrict__ Vt,
    const float* __restrict__ cosp, const float* __restrict__ sinp,
    int M, int N, int K) {
  __shared__ __hip_bfloat16 Al[128 * 32];
  __shared__ __hip_bfloat16 Bl[128 * 32];
  const int nb = N >> 7;
  const int bm = blockIdx.x / nb, bn = blockIdx.x % nb;
  const int m0 = bm << 7, n0 = bn << 7;
  const int tid = threadIdx.x, lane = tid & 63, w = tid >> 6;
  const int wr = w >> 1, wc = w & 1;
  const int lg = lane >> 4, li = lane & 15;
  f32x4 acc[4][4] = {};
  for (int k0 = 0; k0 < K; k0 += 32) {
    __syncthreads();
#pragma unroll
    for (int i = 0; i < 2; ++i) {
      int ci = i * 256 + w * 64 + lane;
      int row = ci >> 2, c8 = (ci & 3) << 3;
      gload_lds16(A + (size_t)(m0 + row) * K + k0 + c8, Al + (size_t)(i * 256 + w * 64) * 8);
      gload_lds16(Bm + (size_t)(n0 + row) * K + k0 + c8, Bl + (size_t)(i * 256 + w * 64) * 8);
    }
    __syncthreads();
    bf16x8 af[4], bfr[4];
#pragma unroll
    for (int f = 0; f < 4; ++f) {
      af[f] = *reinterpret_cast<const bf16x8*>(Al + (wr * 64 + f * 16 + li) * 32 + lg * 8);
      bfr[f] = *reinterpret_cast<const bf16x8*>(Bl + (wc * 64 + f * 16 + li) * 32 + lg * 8);
    }
#pragma unroll
    for (int fm = 0; fm < 4; ++fm)
#pragma unroll
      for (int fn = 0; fn < 4; ++fn)
        acc[fm][fn] = __builtin_amdgcn_mfma_f32_16x16x32_bf16(af[fm], bfr[fn], acc[fm][fn], 0, 0, 0);
  }
  // epilogue: C/D layout row=(lane>>4)*4+j, col=lane&15  [verified m89/m91]
  if constexpr (MODE == 1) {
#pragma unroll
    for (int fm = 0; fm < 4; ++fm)
#pragma unroll
      for (int fn = 0; fn < 4; ++fn) {
        int col = n0 + wc * 64 + fn * 16 + li;
#pragma unroll
        for (int j = 0; j < 4; ++j) {
          int row = m0 + wr * 64 + fm * 16 + lg * 4 + j;
          Cout[(size_t)row * N + col] = acc[fm][fn][j];
        }
      }
  } else {
    const int n0w = n0 + wc * 64;  // wave covers exactly one head's 64 cols
#pragma unroll
    for (int fm = 0; fm < 4; ++fm)
#pragma unroll
      for (int j = 0; j < 4; ++j) {
        int r = m0 + wr * 64 + fm * 16 + lg * 4 + j;
        int b = r >> 11, s = r & 2047;
        if (n0w < 1536) {  // Q or K: apply RoPE (pairs d<32 <-> d+32 are frags fn and fn+2)
#pragma unroll
          for (int fn = 0; fn < 4; ++fn) {
            int d = fn * 16 + li;
            float cv = cosp[(size_t)r * 64 + d];
            float sv = sinp[(size_t)r * 64 + d];
            float x = acc[fm][fn][j];
            float rot = (fn < 2) ? -acc[fm][fn + 2][j] : acc[fm][fn - 2][j];
            __hip_bfloat16 hv = __float2bfloat16(x * cv + rot * sv);
            if (n0w < 1024) {
              int h = n0w >> 6;
              Qb[(((size_t)(b * 16 + h) << 11) + s) * 64 + d] = hv;
            } else {
              int kvh = (n0w - 1024) >> 6;
              Kb[(((size_t)(b * 8 + kvh) << 11) + s) * 64 + d] = hv;
            }
          }
        } else {  // V: no rope, write transposed Vt[b,kvh][d][s]
          int kvh = (n0w - 1536) >> 6;
#pragma unroll
          for (int fn = 0; fn < 4; ++fn) {
            int d = fn * 16 + li;
            Vt[((size_t)(b * 8 + kvh) * 64 + d) * 2048 + s] = __float2bfloat16(acc[fm][fn][j]);
          }
        }
      }
  }
}

// ---------------- fused dynamic-mask flash attention ----------------
// grid: b*16*32 + h*32 + qt ; 4 waves, each owns 16 q-rows; 64-key chunks.
// NOTE: future keys matter (ref adds -1e9, not -inf): rows with all past keys
// dynamic-masked attend uniformly to future keys at exactly -1e9f. So we only
// causally truncate the k-loop for q-tiles >= 4 (q>=256, P(all-masked) < 1e-116).
__global__ __launch_bounds__(256) void attn_kernel(
    const __hip_bfloat16* __restrict__ Qb, const __hip_bfloat16* __restrict__ Kb,
    const __hip_bfloat16* __restrict__ Vt, const float* __restrict__ dyn,
    const float* __restrict__ rate, __hip_bfloat16* __restrict__ AO) {
  __shared__ short Pl[4][1024];  // per-wave P bounce (16x64 bf16, XOR-swizzled)
  const int bid = blockIdx.x;
  const int qt = bid & 31, h = (bid >> 5) & 15, b = bid >> 9;
  const int kvh = h >> 1;
  const int tid = threadIdx.x, lane = tid & 63, w = tid >> 6;
  const int lg = lane >> 4, li = lane & 15;
  const int q0 = qt * 64 + w * 16;
  const __hip_bfloat16* Qp = Qb + ((size_t)(b * 16 + h) << 11) * 64;
  const __hip_bfloat16* Kp = Kb + ((size_t)(b * 8 + kvh) << 11) * 64;
  const __hip_bfloat16* Vp = Vt + ((size_t)(b * 8 + kvh) << 17);
  const float* dynp = dyn + ((size_t)(b * 16 + h) << 11);
  const float rt = rate[b * 16 + h];
  bf16x8 qa0 = *reinterpret_cast<const bf16x8*>(Qp + (size_t)(q0 + li) * 64 + lg * 8);
  bf16x8 qa1 = *reinterpret_cast<const bf16x8*>(Qp + (size_t)(q0 + li) * 64 + 32 + lg * 8);
  f32x4 oa[4] = {};
  float mrow[4], lrow[4];
  int qrow[4];
#pragma unroll
  for (int j = 0; j < 4; ++j) { mrow[j] = FMIN; lrow[j] = 0.f; qrow[j] = q0 + lg * 4 + j; }
  short* pl = &Pl[w][0];
  const int kc_end = (qt >= 4) ? (qt + 1) : 32;
  for (int kc = 0; kc < kc_end; ++kc) {
    const int k0 = kc * 64;
    // S = Q K^T  (two K=32 mfma steps per 16-key col frag)
    f32x4 sf[4];
#pragma unroll
    for (int cf = 0; cf < 4; ++cf) {
      const __hip_bfloat16* kr = Kp + (size_t)(k0 + cf * 16 + li) * 64 + lg * 8;
      bf16x8 kb0 = *reinterpret_cast<const bf16x8*>(kr);
      bf16x8 kb1 = *reinterpret_cast<const bf16x8*>(kr + 32);
      f32x4 z = {};
      z = __builtin_amdgcn_mfma_f32_16x16x32_bf16(qa0, kb0, z, 0, 0, 0);
      z = __builtin_amdgcn_mfma_f32_16x16x32_bf16(qa1, kb1, z, 0, 0, 0);
      sf[cf] = z;
    }
    // scale + dynamic mask + causal (-1e9 added with separate f32 rounding, matching ref)
    float pv[4][4];
    float cmax[4] = {FMIN, FMIN, FMIN, FMIN};
#pragma unroll
    for (int cf = 0; cf < 4; ++cf) {
      int kk = k0 + cf * 16 + li;
      float dv = dynp[kk];
      float mv = (dv < rt) ? FMIN : dv;  // strict <, as reference
#pragma unroll
      for (int j = 0; j < 4; ++j) {
        float sc = sf[cf][j] * 0.125f + mv;
        if (kk > qrow[j]) sc += -1e9f;
        pv[cf][j] = sc;
        cmax[j] = fmaxf(cmax[j], sc);
      }
    }
#pragma unroll
    for (int off = 1; off < 16; off <<= 1)
#pragma unroll
      for (int j = 0; j < 4; ++j)
        cmax[j] = fmaxf(cmax[j], __shfl_xor(cmax[j], off));
    float fsc[4], rsum[4];
#pragma unroll
    for (int j = 0; j < 4; ++j) {
      float mn = fmaxf(mrow[j], cmax[j]);
      fsc[j] = expf(mrow[j] - mn);
      mrow[j] = mn;
      rsum[j] = 0.f;
    }
#pragma unroll
    for (int cf = 0; cf < 4; ++cf)
#pragma unroll
      for (int j = 0; j < 4; ++j) {
        float p = expf(pv[cf][j] - mrow[j]);
        pv[cf][j] = p;
        rsum[j] += p;
      }
#pragma unroll
    for (int off = 1; off < 16; off <<= 1)
#pragma unroll
      for (int j = 0; j < 4; ++j)
        rsum[j] += __shfl_xor(rsum[j], off);
#pragma unroll
    for (int j = 0; j < 4; ++j) lrow[j] = lrow[j] * fsc[j] + rsum[j];
#pragma unroll
    for (int df = 0; df < 4; ++df)
#pragma unroll
      for (int j = 0; j < 4; ++j)
        oa[df][j] *= fsc[j];
    // P (C-layout) -> LDS bf16, XOR-swizzled within 8-elem blocks
#pragma unroll
    for (int cf = 0; cf < 4; ++cf)
#pragma unroll
      for (int j = 0; j < 4; ++j) {
        int r = lg * 4 + j;
        int e = (r << 6) + cf * 16 + li;
        e ^= (r & 7) << 3;
        pl[e] = bf16s(pv[cf][j]);
      }
    // O += P @ V   (A-frag from LDS, B-frag = Vt contiguous global 16B)
#pragma unroll
    for (int m2 = 0; m2 < 2; ++m2) {
      int e = (li << 6) + m2 * 32 + lg * 8;
      e ^= (li & 7) << 3;
      bf16x8 pa = *reinterpret_cast<const bf16x8*>(pl + e);
#pragma unroll
      for (int df = 0; df < 4; ++df) {
        bf16x8 vb = *reinterpret_cast<const bf16x8*>(
            Vp + (size_t)(df * 16 + li) * 2048 + k0 + m2 * 32 + lg * 8);
        oa[df] = __builtin_amdgcn_mfma_f32_16x16x32_bf16(pa, vb, oa[df], 0, 0, 0);
      }
    }
  }
#pragma unroll
  for (int df = 0; df < 4; ++df)
#pragma unroll
    for (int j = 0; j < 4; ++j) {
      float o = oa[df][j] / lrow[j];
      int q = q0 + lg * 4 + j;
      int d = df * 16 + li;
      AO[((size_t)((b << 11) + q)) * 1024 + (h << 6) + d] = __float2bfloat16(o);
    }
}

extern "C" void kernel_launch(void* const* d_in, const int* in_sizes, int n_in,
                              void* d_out, int out_size, void* d_ws, size_t ws_size,
                              hipStream_t stream) {
  const float* hidden = (const float*)d_in[0];
  const float* cosp   = (const float*)d_in[1];
  const float* sinp   = (const float*)d_in[2];
  // d_in[3] = attention_mask: pure causal (0 / -1e9), computed analytically.
  const float* Wq  = (const float*)d_in[4];
  const float* Wk  = (const float*)d_in[5];
  const float* Wv  = (const float*)d_in[6];
  const float* Av  = (const float*)d_in[7];
  const float* Wdt = (const float*)d_in[8];
  const float* Wo  = (const float*)d_in[9];
  float* out = (float*)d_out;

  char* ws = (char*)d_ws;
  size_t off = 0;
  auto alloc = [&](size_t bytes) {
    char* p = ws + off;
    off += (bytes + 255) & ~(size_t)255;
    return (void*)p;
  };
  __hip_bfloat16* hb   = (__hip_bfloat16*)alloc(4096ULL * 1024 * 2);  // hidden bf16
  __hip_bfloat16* wqkv = (__hip_bfloat16*)alloc(2048ULL * 1024 * 2);  // [Wq;Wk;Wv] bf16
  __hip_bfloat16* wob  = (__hip_bfloat16*)alloc(1024ULL * 1024 * 2);  // Wo bf16
  __hip_bfloat16* Qb   = (__hip_bfloat16*)alloc(2ULL * 16 * 2048 * 64 * 2);  // (b,h,s,d)
  __hip_bfloat16* Kb   = (__hip_bfloat16*)alloc(2ULL * 8 * 2048 * 64 * 2);   // (b,kvh,s,d)
  __hip_bfloat16* Vt   = (__hip_bfloat16*)alloc(2ULL * 8 * 2048 * 64 * 2);   // (b,kvh,d,s)
  float* wcomb = (float*)alloc(16ULL * 1024 * 4);
  float* dynb  = (float*)alloc(2ULL * 16 * 2048 * 4);  // (b,h,s)
  float* rateb = (float*)alloc(256);
  __hip_bfloat16* ao = (__hip_bfloat16*)alloc(4096ULL * 1024 * 2);  // attn out (bs, h*64+d)

  cvt_kernel<<<4096, 256, 0, stream>>>(hidden, hb, 1048576);
  cvt_kernel<<<1024, 256, 0, stream>>>(Wq, wqkv, 262144);
  cvt_kernel<<<512, 256, 0, stream>>>(Wk, wqkv + 1024 * 1024, 131072);
  cvt_kernel<<<512, 256, 0, stream>>>(Wv, wqkv + 1536 * 1024, 131072);
  cvt_kernel<<<1024, 256, 0, stream>>>(Wo, wob, 262144);
  wcomb_kernel<<<64, 256, 0, stream>>>(Wdt, Wv, wcomb);
  gemm_bt<0><<<512, 256, 0, stream>>>(hb, wqkv, nullptr, Qb, Kb, Vt, cosp, sinp,
                                      4096, 2048, 1024);
  dyn_kernel<<<256, 256, 0, stream>>>(hidden, wcomb, Av, dynb);
  rate_kernel<<<32, 256, 0, stream>>>(dynb, rateb);
  attn_kernel<<<1024, 256, 0, stream>>>(Qb, Kb, Vt, dynb, rateb, ao);
  gemm_bt<1><<<256, 256, 0, stream>>>(ao, wob, out, nullptr, nullptr, nullptr,
                                      nullptr, nullptr, 4096, 1024, 1024);
}